// Round 2
// baseline (1047.860 us; speedup 1.0000x reference)
//
#include <hip/hip_runtime.h>
#include <hip/hip_bf16.h>
#include <stdint.h>
#include <math.h>

#define T_SEQ 2048
#define D_IN  1024
#define H1_N  512

typedef short  short8  __attribute__((ext_vector_type(8)));
typedef __bf16 bf16x8  __attribute__((ext_vector_type(8)));
typedef float  floatx4 __attribute__((ext_vector_type(4)));

#if defined(__HIP_DEVICE_COMPILE__) && __has_builtin(__builtin_amdgcn_global_load_lds)
#define HAS_GLL 1
#endif

__device__ __forceinline__ short f2bf(float f) {
    union { float f; unsigned u; } v; v.f = f;
    unsigned r = v.u + 0x7fffu + ((v.u >> 16) & 1u);   // RNE
    return (short)(r >> 16);
}

// ---------------------------------------------------------------------------
// Prep: W1 [D,H1] fp32 -> W1T [H1][D] bf16(short) via coalesced LDS transpose;
// block 128 computes w_eff = W2@W3, c_eff = b2.W3 + b3, and zeroes the per-b
// completion counters used by the fused topk (ws is poison-filled each iter).
// ---------------------------------------------------------------------------
__global__ __launch_bounds__(256)
void prep_kernel(const float* __restrict__ W1, const float* __restrict__ W2,
                 const float* __restrict__ b2, const float* __restrict__ W3,
                 const float* __restrict__ b3, short* __restrict__ W1T,
                 float* __restrict__ weff, float* __restrict__ ceff,
                 unsigned* __restrict__ ctr) {
    const int t = threadIdx.x;
    if (blockIdx.x == 128) {
        for (int h = t; h < H1_N; h += 256) {
            float s = 0.f;
            for (int k = 0; k < 32; ++k) s += W2[h * 32 + k] * W3[k];
            weff[h] = s;
        }
        if (t < 64) ctr[t] = 0u;           // per-batch completion counters
        if (t == 0) {
            float s = 0.f;
            for (int k = 0; k < 32; ++k) s += b2[k] * W3[k];
            *ceff = s + b3[0];
        }
        return;
    }
    __shared__ float tile[64][65];
    const int dx = blockIdx.x >> 3;        // 0..15  -> d0 = dx*64
    const int ny = blockIdx.x & 7;         // 0..7   -> n0 = ny*64
    const int d0 = dx * 64, n0 = ny * 64;
#pragma unroll
    for (int i = 0; i < 16; ++i) {
        int e = i * 256 + t;               // 0..4095
        int r = e >> 6, c = e & 63;
        tile[r][c] = W1[(size_t)(d0 + r) * H1_N + n0 + c];
    }
    __syncthreads();
#pragma unroll
    for (int i = 0; i < 8; ++i) {
        int o = i * 512 + t * 2;           // pairs
        int rr = o >> 6, cc = o & 63;
        unsigned lo = (unsigned short)f2bf(tile[cc][rr]);
        unsigned hi = (unsigned short)f2bf(tile[cc + 1][rr]);
        *(unsigned*)&W1T[(size_t)(n0 + rr) * D_IN + d0 + cc] = lo | (hi << 16);
    }
}

// ---- raw-barrier pipeline primitives (rule #18: sched_barrier after waits) --
#define BARRIER_   do { __builtin_amdgcn_s_barrier(); __builtin_amdgcn_sched_barrier(0); } while (0)
#define WAITLGKM0_ do { asm volatile("s_waitcnt lgkmcnt(0)" ::: "memory"); __builtin_amdgcn_sched_barrier(0); } while (0)
#define WAITVM4_   do { asm volatile("s_waitcnt vmcnt(4)"   ::: "memory"); __builtin_amdgcn_sched_barrier(0); } while (0)
#define WAITVM0_   do { asm volatile("s_waitcnt vmcnt(0)"   ::: "memory"); __builtin_amdgcn_sched_barrier(0); } while (0)

// ---------------------------------------------------------------------------
// Fused GEMM1 + relu + (.w_eff) + sigmoid -> logits[B,T], plus fused top-k
// (last live block per batch runs the radix-select, T4-style counted-vmcnt
// pipeline: gll-B 1 slab ahead (L2, ~300cy), reg-A 2 slabs ahead (HBM,
// ~900cy); raw s_barrier, NO vmcnt(0) drain in steady state. vmem per iter:
// 8 gll (B) + 4 dwordx4 (A) -> end-of-iter s_waitcnt vmcnt(4) forces
// A(i+1)+B(i+1) complete while A(i+2) stays in flight.
// ---------------------------------------------------------------------------
__global__ __launch_bounds__(512, 2)
void gemm_kernel(const float* __restrict__ avf, const int* __restrict__ seq_len,
                 const float* __restrict__ b1, const short* __restrict__ W1T,
                 const float* __restrict__ weff, const float* __restrict__ ceff_p,
                 float* __restrict__ logits, unsigned* __restrict__ ctr,
                 float* __restrict__ out) {
    const int b  = blockIdx.y;
    const int t0 = blockIdx.x * 128;
    const int seq = seq_len[b];
    if (t0 >= seq) return;                 // fully-masked tile

    __shared__ short Bs[2][H1_N * 64];     // 2 x 64KB, XOR-swizzled [n][k-chunk]
    __shared__ short As[128 * 72];         // 18KB, rows padded 64->72 elems
    __shared__ float red[128];
    __shared__ int   sflag;
    __shared__ unsigned sh_sel, sh_want;

    const int t   = threadIdx.x;
    const int w   = t >> 6;                // 0..7
    const int l   = t & 63;
    const int q   = l >> 4;                // quad
    const int m16 = l & 15;
    const int wn  = (w & 3) * 128;         // wave col base
    const int wm  = (w >> 2) * 64;         // wave row base

    if (t < 128) red[t] = 0.f;

    floatx4 acc[4][8];
#pragma unroll
    for (int i = 0; i < 4; ++i)
#pragma unroll
        for (int j = 0; j < 8; ++j) acc[i][j] = (floatx4){0.f, 0.f, 0.f, 0.f};

    // A-slot assignment: two 8-elem slots per thread, rows CLAMPED to seq-1
    // (unconditional loads -> exact vmcnt bookkeeping; dup rows hit L2)
    const int am0 = t >> 3, ac0 = t & 7;               // slot 0: rows 0..63
    const int am1 = 64 + (t >> 3), ac1 = t & 7;        // slot 1: rows 64..127
    int gr0 = t0 + am0; if (gr0 >= seq) gr0 = seq - 1;
    int gr1 = t0 + am1; if (gr1 >= seq) gr1 = seq - 1;
    const float* aptr0 = avf + ((size_t)b * T_SEQ + gr0) * D_IN + ac0 * 8;
    const float* aptr1 = avf + ((size_t)b * T_SEQ + gr1) * D_IN + ac1 * 8;

    float4 apreA[2][2], apreB[2][2];       // 2 sets x 16 fp32 (2-slab-ahead A)

    // ---- issue B gll for slab k0 into Bs[nxt] (swizzled gather); order-pinned
    auto stageB = [&](int k0, int nxt) {
#pragma unroll
        for (int i = 0; i < 8; ++i) {
            int s = w * 512 + i * 64 + l;              // 16B slot id, 0..4095
            int n = s >> 3;
            int c = (s & 7) ^ (n & 7);                 // source chunk (XOR swizzle)
            const short* gsrc = W1T + (size_t)n * D_IN + k0 + c * 8;
#ifdef HAS_GLL
            __builtin_amdgcn_global_load_lds(
                (const __attribute__((address_space(1))) unsigned int*)gsrc,
                (__attribute__((address_space(3))) unsigned int*)((char*)&Bs[nxt][0] + (w * 512 + i * 64) * 16),
                16, 0, 0);
#else
            *(short8*)((char*)&Bs[nxt][0] + (size_t)s * 16) = *(const short8*)gsrc;
#endif
        }
        __builtin_amdgcn_sched_barrier(0);  // pin: gll issue BEFORE A loads
    };

#define LOADA(K0, APRE) do {                                                  \
        const float* _g0 = aptr0 + (K0);                                      \
        (APRE)[0][0] = *(const float4*)_g0;                                   \
        (APRE)[0][1] = *(const float4*)(_g0 + 4);                             \
        const float* _g1 = aptr1 + (K0);                                      \
        (APRE)[1][0] = *(const float4*)_g1;                                   \
        (APRE)[1][1] = *(const float4*)(_g1 + 4);                             \
    } while (0)

#define WRITEA(APRE) do {                                                     \
        short8 _v;                                                            \
        _v[0] = f2bf((APRE)[0][0].x); _v[1] = f2bf((APRE)[0][0].y);           \
        _v[2] = f2bf((APRE)[0][0].z); _v[3] = f2bf((APRE)[0][0].w);           \
        _v[4] = f2bf((APRE)[0][1].x); _v[5] = f2bf((APRE)[0][1].y);           \
        _v[6] = f2bf((APRE)[0][1].z); _v[7] = f2bf((APRE)[0][1].w);           \
        *(short8*)(&As[am0 * 72 + ac0 * 8]) = _v;                             \
        _v[0] = f2bf((APRE)[1][0].x); _v[1] = f2bf((APRE)[1][0].y);           \
        _v[2] = f2bf((APRE)[1][0].z); _v[3] = f2bf((APRE)[1][0].w);           \
        _v[4] = f2bf((APRE)[1][1].x); _v[5] = f2bf((APRE)[1][1].y);           \
        _v[6] = f2bf((APRE)[1][1].z); _v[7] = f2bf((APRE)[1][1].w);           \
        *(short8*)(&As[am1 * 72 + ac1 * 8]) = _v;                             \
    } while (0)

    int cur = 0;
    auto computeTile = [&]() {
#pragma unroll
        for (int kt = 0; kt < 2; ++kt) {
            short8 af[4], bfr[8];
#pragma unroll
            for (int mt = 0; mt < 4; ++mt)
                af[mt] = *(const short8*)(&As[(wm + mt * 16 + m16) * 72 + kt * 32 + q * 8]);
#pragma unroll
            for (int nt = 0; nt < 8; ++nt) {
                int n = wn + nt * 16 + m16;
                int c = (kt * 4 + q) ^ (n & 7);
                bfr[nt] = *(const short8*)((char*)&Bs[cur][0] + (size_t)(n * 8 + c) * 16);
            }
#pragma unroll
            for (int mt = 0; mt < 4; ++mt)
#pragma unroll
                for (int nt = 0; nt < 8; ++nt)
                    acc[mt][nt] = __builtin_amdgcn_mfma_f32_16x16x32_bf16(
                        __builtin_bit_cast(bf16x8, af[mt]),
                        __builtin_bit_cast(bf16x8, bfr[nt]),
                        acc[mt][nt], 0, 0, 0);
        }
    };

    // ---- prologue: B(0) gll + A(0),A(1) reg loads; write A(0); one barrier --
    stageB(0, 0);
    LOADA(0, apreA);           // issue order/wave: 8 gll, A0 x4, A1 x4
    LOADA(64, apreB);
    WRITEA(apreA);             // compiler waits apreA -> forces gll(B0) done too
    WAITLGKM0_;
    BARRIER_;

    // ---- main loop: 16 K-slabs, unrolled x2 so apre set index is static ----
#define GITER(IT, APRE) do {                                                  \
        if ((IT) > 0) { WRITEA(APRE); WAITLGKM0_; BARRIER_; }                 \
        if ((IT) < 15) stageB(((IT) + 1) * 64, cur ^ 1);                      \
        if ((IT) < 14) LOADA(((IT) + 2) * 64, APRE);                          \
        computeTile();                                                        \
        if ((IT) < 14)       { WAITVM4_; BARRIER_; }                          \
        else if ((IT) == 14) { WAITVM0_; BARRIER_; }                          \
        cur ^= 1;                                                             \
    } while (0)

    for (int itt = 0; itt < 8; ++itt) {
        GITER(2 * itt,     apreA);
        GITER(2 * itt + 1, apreB);
    }
#undef GITER

    // ---- epilogue: logit_row += relu(h + b1) . w_eff, fused per lane ----
    float bv[8], wv[8];
#pragma unroll
    for (int nt = 0; nt < 8; ++nt) {
        int col = wn + nt * 16 + m16;
        bv[nt] = b1[col];
        wv[nt] = weff[col];
    }
#pragma unroll
    for (int mt = 0; mt < 4; ++mt) {
#pragma unroll
        for (int r = 0; r < 4; ++r) {
            float p = 0.f;
#pragma unroll
            for (int nt = 0; nt < 8; ++nt) {
                float h = acc[mt][nt][r] + bv[nt];
                p += fmaxf(h, 0.f) * wv[nt];
            }
#pragma unroll
            for (int off = 1; off < 16; off <<= 1) p += __shfl_xor(p, off, 64);
            if (m16 == 0) atomicAdd(&red[wm + mt * 16 + q * 4 + r], p);
        }
    }
    __syncthreads();
    if (t < 128) {
        float x = red[t] + ceff_p[0];
        logits[(size_t)b * T_SEQ + t0 + t] = 1.f / (1.f + __expf(-x));
    }

    // ---- fused top-k: last live block of batch b does the radix-select ----
    const int nlive = (seq + 127) >> 7;    // #live tiles for this b (>=1)
    __syncthreads();                        // logits stores complete (vmcnt 0)
    if (t == 0) {
        __threadfence();                    // release: publish logits
        unsigned prev = atomicAdd(&ctr[b], 1u);   // device-scope
        sflag = (prev == (unsigned)(nlive - 1)) ? 1 : 0;
    }
    __syncthreads();
    if (!sflag) return;
    __threadfence();                        // acquire: see other blocks' logits

    // topk scratch overlays Bs (dead after main loop + barriers above)
    unsigned* hist = (unsigned*)&Bs[0][0];
    unsigned* sfA  = hist + 256;
    unsigned* sfB  = sfA + 256;
    float*    rs   = (float*)(sfB + 256);
    unsigned* rc   = (unsigned*)(rs + 8);

    const int ks = seq / 16 + 1;            // 2..129, always <= seq
    const float* lg = logits + (size_t)b * T_SEQ;
    float rv[4];
#pragma unroll
    for (int j = 0; j < 4; ++j) {
        int i = j * 512 + t;
        rv[j] = (i < seq) ? lg[i] : 0.0f;   // sentinel 0 < any sigmoid output
    }

    unsigned prefix = 0;
    unsigned want = (unsigned)ks;
    for (int shift = 24; shift >= 0; shift -= 8) {
        const unsigned maskHi = (shift == 24) ? 0u : (0xFFFFFFFFu << (shift + 8));
        if (t < 256) hist[t] = 0;
        __syncthreads();
#pragma unroll
        for (int j = 0; j < 4; ++j) {
            unsigned u = __float_as_uint(rv[j]);
            if ((u & maskHi) == (prefix & maskHi))
                atomicAdd(&hist[(u >> shift) & 0xFF], 1u);
        }
        __syncthreads();
        if (t < 256) sfA[t] = hist[t];
        __syncthreads();
        unsigned* src = sfA; unsigned* dst = sfB;
#pragma unroll
        for (int off = 1; off < 256; off <<= 1) {
            if (t < 256) dst[t] = src[t] + ((t + off < 256) ? src[t + off] : 0u);
            __syncthreads();
            unsigned* tmp = src; src = dst; dst = tmp;
        }
        if (t < 256) {
            unsigned ge = src[t];
            unsigned ge_next = (t < 255) ? src[t + 1] : 0u;
            if (ge >= want && ge_next < want) {      // exactly one thread
                sh_sel = (unsigned)t;
                sh_want = want - ge_next;
            }
        }
        __syncthreads();
        prefix |= sh_sel << shift;
        want = sh_want;
    }

    const float pivot = __uint_as_float(prefix);
    float s = 0.f; unsigned cgt = 0;
#pragma unroll
    for (int j = 0; j < 4; ++j) {
        float x = rv[j];
        if (x > pivot) { s += x; cgt++; }
    }
#pragma unroll
    for (int off = 32; off > 0; off >>= 1) {
        s   += __shfl_down(s, off, 64);
        cgt += __shfl_down(cgt, off, 64);
    }
    if (l == 0) { rs[w] = s; rc[w] = cgt; }
    __syncthreads();
    if (t == 0) {
        float S = 0.f; unsigned C = 0;
#pragma unroll
        for (int i = 0; i < 8; ++i) { S += rs[i]; C += rc[i]; }
        out[b] = (S + (float)(ks - (int)C) * pivot) / (float)ks;
    }
#undef LOADA
#undef WRITEA
}

// ---------------------------------------------------------------------------
extern "C" void kernel_launch(void* const* d_in, const int* in_sizes, int n_in,
                              void* d_out, int out_size, void* d_ws, size_t ws_size,
                              hipStream_t stream) {
    const float* avf = (const float*)d_in[0];
    const int*   seq = (const int*)  d_in[1];
    const float* W1  = (const float*)d_in[2];
    const float* b1  = (const float*)d_in[3];
    const float* W2  = (const float*)d_in[4];
    const float* b2  = (const float*)d_in[5];
    const float* W3  = (const float*)d_in[6];
    const float* b3  = (const float*)d_in[7];
    float* out = (float*)d_out;

    // workspace layout
    short* W1T      = (short*)d_ws;                       // 512*1024*2 = 1 MB
    float* weff     = (float*)((char*)d_ws + (1 << 20));  // 512 floats
    float* ceff     = weff + 512;                         // 1 float
    float* logits   = weff + 1024;                        // B*T floats (512 KB)
    unsigned* ctr   = (unsigned*)(logits + 64 * T_SEQ);   // 64 counters

    prep_kernel<<<dim3(129), dim3(256), 0, stream>>>(W1, W2, b2, W3, b3, W1T, weff, ceff, ctr);
    gemm_kernel<<<dim3(T_SEQ / 128, 64), dim3(512), 0, stream>>>(avf, seq, b1, W1T, weff, ceff, logits, ctr, out);
}